// Round 1
// baseline (7055.361 us; speedup 1.0000x reference)
//
#include <hip/hip_runtime.h>

// ---------------- problem constants ----------------
#define S_LEN 512
#define HID   512
#define IN_D  64
#define GATES 2048            // 4*HID
#define K0    576             // IN_D + HID
#define K1    1024            // HID + HID
#define KP0   578             // padded LDS stride (bytes/4 % 32 == 1 -> conflict-free)
#define KP1   1026
#define CLUSTERS 4
#define WGS   64              // workgroups per cluster
#define BPC   16              // batch rows per cluster
#define NBLOCKS 256
#define NTHREADS 256

typedef _Float16 f16;
typedef _Float16 f16x8 __attribute__((ext_vector_type(8)));
typedef float    f32x4 __attribute__((ext_vector_type(4)));

// ---------------- LDS layout (dynamic) ----------------
#define LDS_W0_OFF  0
#define LDS_W1_OFF  (32 * KP0 * 2)                    // 36992
#define LDS_STG_OFF (LDS_W1_OFF + 32 * KP1 * 2)      // 102656
#define LDS_TOTAL   (LDS_STG_OFF + 4 * 16 * 17 * 4)  // 107008 bytes

// ---------------- workspace layout ----------------
// [0 .. 4096): per-cluster barrier blocks (256 B apart): [0]=count, [1]=phase
// [4096 ..  ): h planes: per cluster 128 KB:
//    layer (2) x parity (2) x {hi,lo} (2) x [16 rows][512 cols] f16 (16 KB each)
#define WS_BAR_OFF 0
#define WS_H_OFF   4096
#define CL_STRIDE  131072
#define L_STRIDE   65536
#define P_STRIDE   32768
#define PL_STRIDE  16384
#define WS_NEED    (WS_H_OFF + CLUSTERS * CL_STRIDE)   // 528384 bytes

__device__ __forceinline__ float sigf(float v) {
  v = fminf(fmaxf(v, -30.f), 30.f);
  return 1.f / (1.f + __expf(-v));
}
__device__ __forceinline__ float tanh_f(float v) {
  v = fminf(fmaxf(v, -15.f), 15.f);
  float e = __expf(2.f * v);
  return (e - 1.f) / (e + 1.f);
}

extern "C" __global__ void __launch_bounds__(NTHREADS, 1)
lstm_persist(const float* __restrict__ x,  const float* __restrict__ W0,
             const float* __restrict__ b0, const float* __restrict__ W1,
             const float* __restrict__ b1, const float* __restrict__ Wfc,
             const float* __restrict__ bfc, float* __restrict__ out,
             unsigned char* __restrict__ ws)
{
  extern __shared__ char lds[];
  f16*   w0l     = (f16*)(lds + LDS_W0_OFF);
  f16*   w1l     = (f16*)(lds + LDS_W1_OFF);
  float* stgbase = (float*)(lds + LDS_STG_OFF);

  const int tid   = threadIdx.x;
  const int wg    = blockIdx.x & (WGS - 1);   // wg index within cluster
  const int cl    = blockIdx.x / WGS;         // cluster id
  const int wave  = tid >> 6;
  const int lane  = tid & 63;
  const int hbase = wg * 8;                   // 8 h-cols per wg per layer

  // ---- one-time: gather + transpose this WG's weight columns into LDS (fp16) ----
  {
    const int nl = tid & 31;                  // n_local 0..31
    const int tile = nl >> 4, wi = nl & 15, g = wi >> 2, jj = wi & 3;
    const int col = g * HID + hbase + tile * 4 + jj;
    for (int k = tid >> 5; k < K0; k += 8)
      w0l[nl * KP0 + k] = (f16)W0[(size_t)k * GATES + col];
    for (int k = tid >> 5; k < K1; k += 8)
      w1l[nl * KP1 + k] = (f16)W1[(size_t)k * GATES + col];
  }
  __syncthreads();

  // ---- per-wave constants ----
  const int layer = wave >> 1;                // waves 0-1: layer0, 2-3: layer1
  const int tile  = wave & 1;                 // n-tile (16 gate cols) within WG
  const int cb    = hbase + tile * 4;         // global hcol base of this wave
  const int erow  = lane >> 2;                // epilogue batch row 0..15
  const int ehc   = lane & 3;                 // epilogue hcol offset 0..3
  const int hcol  = cb + ehc;
  const float* bsrc = layer ? b1 : b0;
  const float bg0 = bsrc[0 * HID + hcol];
  const float bg1 = bsrc[1 * HID + hcol];
  const float bg2 = bsrc[2 * HID + hcol];
  const float bg3 = bsrc[3 * HID + hcol];
  float cstate = 0.f;                         // persistent cell state (1 VGPR)
  float* stg = stgbase + wave * (16 * 17);

  const int fm  = lane & 15;                  // A row (batch) / B row (n) in frags
  const int q8  = (lane >> 4) * 8;            // k offset within 32-k block
  const int brow = cl * BPC + fm;             // global batch row for A frags

  unsigned char* hbb = ws + WS_H_OFF + (size_t)cl * CL_STRIDE;
  unsigned int* bar = (unsigned int*)(ws + (size_t)cl * 256);

  auto plane = [&](int lyr, int par, int hl) -> f16* {
    return (f16*)(hbb + lyr * L_STRIDE + par * P_STRIDE + hl * PL_STRIDE);
  };

  unsigned int target = 1u;

  // phase n: compute layer0(t=n+1) [reads h0(n)] and layer1(t=n) [reads h0(n), h1(n-1)]
  // h0(t) lives in parity t&1; h1(t) in parity t&1. n=-1 is the layer0 prologue.
  for (int n = -1; n < S_LEN; ++n) {
    f32x4 acc = {0.f, 0.f, 0.f, 0.f};
    bool active;
    if (layer == 0) {
      const int t = n + 1;
      active = (t < S_LEN);
      if (active) {
        // x part (K rows 0..63 of W0), fp32 -> fp16 on the fly
        const float* xr = x + ((size_t)brow * S_LEN + t) * IN_D + q8;
        #pragma unroll
        for (int kb = 0; kb < 2; ++kb) {
          f32x4 xa = *(const f32x4*)(xr + kb * 32);
          f32x4 xb = *(const f32x4*)(xr + kb * 32 + 4);
          f16x8 a = { (f16)xa[0], (f16)xa[1], (f16)xa[2], (f16)xa[3],
                      (f16)xb[0], (f16)xb[1], (f16)xb[2], (f16)xb[3] };
          f16x8 bf = *(const f16x8*)(w0l + (tile * 16 + fm) * KP0 + kb * 32 + q8);
          acc = __builtin_amdgcn_mfma_f32_16x16x32_f16(a, bf, acc, 0, 0, 0);
        }
        // h0 part (K rows 64..575), hi+lo split A, shared B
        const f16* hpi = plane(0, n & 1, 0);
        const f16* hpl = plane(0, n & 1, 1);
        #pragma unroll 4
        for (int kb = 0; kb < 16; ++kb) {
          const int k = kb * 32 + q8;
          f16x8 bf = *(const f16x8*)(w0l + (tile * 16 + fm) * KP0 + IN_D + k);
          f16x8 ah = *(const f16x8*)(hpi + fm * HID + k);
          f16x8 al = *(const f16x8*)(hpl + fm * HID + k);
          acc = __builtin_amdgcn_mfma_f32_16x16x32_f16(ah, bf, acc, 0, 0, 0);
          acc = __builtin_amdgcn_mfma_f32_16x16x32_f16(al, bf, acc, 0, 0, 0);
        }
      }
    } else {
      active = (n >= 0);
      if (active) {
        const f16* h0i = plane(0, n & 1, 0);
        const f16* h0l = plane(0, n & 1, 1);
        #pragma unroll 4
        for (int kb = 0; kb < 16; ++kb) {
          const int k = kb * 32 + q8;
          f16x8 bf = *(const f16x8*)(w1l + (tile * 16 + fm) * KP1 + k);
          f16x8 ah = *(const f16x8*)(h0i + fm * HID + k);
          f16x8 al = *(const f16x8*)(h0l + fm * HID + k);
          acc = __builtin_amdgcn_mfma_f32_16x16x32_f16(ah, bf, acc, 0, 0, 0);
          acc = __builtin_amdgcn_mfma_f32_16x16x32_f16(al, bf, acc, 0, 0, 0);
        }
        const f16* h1i = plane(1, (n - 1) & 1, 0);
        const f16* h1l = plane(1, (n - 1) & 1, 1);
        #pragma unroll 4
        for (int kb = 0; kb < 16; ++kb) {
          const int k = kb * 32 + q8;
          f16x8 bf = *(const f16x8*)(w1l + (tile * 16 + fm) * KP1 + HID + k);
          f16x8 ah = *(const f16x8*)(h1i + fm * HID + k);
          f16x8 al = *(const f16x8*)(h1l + fm * HID + k);
          acc = __builtin_amdgcn_mfma_f32_16x16x32_f16(ah, bf, acc, 0, 0, 0);
          acc = __builtin_amdgcn_mfma_f32_16x16x32_f16(al, bf, acc, 0, 0, 0);
        }
      }
    }

    if (active) {
      // acc -> LDS staging (C/D layout: col=lane&15, row=(lane>>4)*4+r)
      #pragma unroll
      for (int r = 0; r < 4; ++r)
        stg[((lane >> 4) * 4 + r) * 17 + fm] = acc[r];
      // same-wave LDS RAW; compiler inserts lgkmcnt waits
      float iv = stg[erow * 17 + 0 + ehc]  + bg0;
      float fv = stg[erow * 17 + 4 + ehc]  + bg1;
      float gv = stg[erow * 17 + 8 + ehc]  + bg2;
      float ov = stg[erow * 17 + 12 + ehc] + bg3;
      float ig = sigf(iv), fg = sigf(fv), gg = tanh_f(gv), og = sigf(ov);
      cstate = fg * cstate + ig * gg;
      float h = og * tanh_f(cstate);

      // gather col-pairs via shfl, write hi/lo planes as agent-coherent u32 stores
      const int src0 = fm * 4 + ((lane >> 4) & 1) * 2;
      float ha = __shfl(h, src0, 64);
      float hb = __shfl(h, src0 + 1, 64);
      if (lane < 32) {
        const int wrow = lane & 15, wpair = lane >> 4;
        const int wpar = (layer == 0) ? ((n + 1) & 1) : (n & 1);
        f16* phi = plane(layer, wpar, 0);
        f16* plo = plane(layer, wpar, 1);
        f16 hah = (f16)ha; f16 hal = (f16)(ha - (float)hah);
        f16 hbh = (f16)hb; f16 hbl = (f16)(hb - (float)hbh);
        unsigned int hw = (unsigned int)__builtin_bit_cast(unsigned short, hah) |
                          ((unsigned int)__builtin_bit_cast(unsigned short, hbh) << 16);
        unsigned int lw = (unsigned int)__builtin_bit_cast(unsigned short, hal) |
                          ((unsigned int)__builtin_bit_cast(unsigned short, hbl) << 16);
        const int coff = wrow * HID + cb + wpair * 2;
        __hip_atomic_store((unsigned int*)(phi + coff), hw, __ATOMIC_RELAXED, __HIP_MEMORY_SCOPE_AGENT);
        __hip_atomic_store((unsigned int*)(plo + coff), lw, __ATOMIC_RELAXED, __HIP_MEMORY_SCOPE_AGENT);
      }
    }

    // ---- cluster barrier (64 WGs) ----
    __syncthreads();   // drains vmcnt: all sc1 h-stores ack'd at coherence point
    if (tid == 0) {
      unsigned int old = __hip_atomic_fetch_add(&bar[0], 1u, __ATOMIC_RELAXED, __HIP_MEMORY_SCOPE_AGENT);
      if (old == WGS - 1) {
        __hip_atomic_store(&bar[0], 0u, __ATOMIC_RELAXED, __HIP_MEMORY_SCOPE_AGENT);
        __hip_atomic_store(&bar[1], target, __ATOMIC_RELEASE, __HIP_MEMORY_SCOPE_AGENT);
      } else {
        while (__hip_atomic_load(&bar[1], __ATOMIC_RELAXED, __HIP_MEMORY_SCOPE_AGENT) < target)
          __builtin_amdgcn_s_sleep(1);
      }
      __builtin_amdgcn_fence(__ATOMIC_ACQUIRE, "agent");  // invalidate L1/L2 -> fresh h reads
    }
    __syncthreads();
    ++target;
  }

  // ---- output head: WG0 of each cluster, h1(511) is in parity 1 ----
  if (wg == 0) {
    const f16* h1i = plane(1, (S_LEN - 1) & 1, 0);
    const f16* h1l = plane(1, (S_LEN - 1) & 1, 1);
    #pragma unroll
    for (int rr = 0; rr < 4; ++rr) {
      const int r = wave * 4 + rr;
      float sum = 0.f;
      for (int k = lane; k < HID; k += 64) {
        float hv = (float)h1i[r * HID + k] + (float)h1l[r * HID + k];
        sum += hv * Wfc[k];
      }
      #pragma unroll
      for (int off = 32; off > 0; off >>= 1)
        sum += __shfl_down(sum, off, 64);
      if (lane == 0) out[cl * BPC + r] = sum + bfc[0];
    }
  }
}

extern "C" void kernel_launch(void* const* d_in, const int* in_sizes, int n_in,
                              void* d_out, int out_size, void* d_ws, size_t ws_size,
                              hipStream_t stream) {
  const float* x   = (const float*)d_in[0];
  const float* W0  = (const float*)d_in[1];
  const float* b0  = (const float*)d_in[2];
  const float* W1  = (const float*)d_in[3];
  const float* b1  = (const float*)d_in[4];
  const float* Wfc = (const float*)d_in[5];
  const float* bfc = (const float*)d_in[6];
  float* out = (float*)d_out;
  unsigned char* ws = (unsigned char*)d_ws;

  (void)in_sizes; (void)n_in; (void)out_size; (void)ws_size;

  // allow >64KB dynamic LDS (idempotent, host-side, capture-safe)
  hipFuncSetAttribute((const void*)lstm_persist,
                      hipFuncAttributeMaxDynamicSharedMemorySize, LDS_TOTAL);

  // zero barrier state + h parity buffers (ws is poisoned 0xAA before every call)
  hipMemsetAsync(ws, 0, WS_NEED, stream);

  void* args[] = { &x, &W0, &b0, &W1, &b1, &Wfc, &bfc, &out, &ws };
  hipLaunchCooperativeKernel((void*)lstm_persist, dim3(NBLOCKS), dim3(NTHREADS),
                             args, LDS_TOTAL, stream);
}

// Round 2
// 6768.654 us; speedup vs baseline: 1.0424x; 1.0424x over previous
//
#include <hip/hip_runtime.h>

// ---------------- problem constants ----------------
#define S_LEN 512
#define HID   512
#define IN_D  64
#define GATES 2048            // 4*HID
#define K0    576             // IN_D + HID
#define K1    1024            // HID + HID
#define KP0   578             // padded LDS stride (dwords % 32 == 1 -> conflict-free B reads)
#define KP1   1026
#define CLUSTERS 4
#define WGS   64              // workgroups per cluster
#define BPC   16              // batch rows per cluster
#define NBLOCKS 256
#define NTHREADS 256

typedef _Float16 f16;
typedef _Float16 f16x8 __attribute__((ext_vector_type(8)));
typedef float    f32x4 __attribute__((ext_vector_type(4)));

// ---------------- LDS layout (dynamic) ----------------
#define LDS_W0_OFF  0
#define LDS_W1_OFF  (32 * KP0 * 2)                    // 36992
#define LDS_STG_OFF (LDS_W1_OFF + 32 * KP1 * 2)      // 102656
#define LDS_TOTAL   (LDS_STG_OFF + 4 * 16 * 17 * 4)  // 107008 bytes

// ---------------- workspace layout ----------------
// [0 .. 64K): flags. cluster c: f0 (128 u32) at c*8192, f1 at c*8192+4096.
// [64K .. ): versioned h slots: (cl*2+layer)*Wn + (t & wmask), 32 KB each
//            (hi plane 16 KB [16 rows][512 cols] f16, then lo plane 16 KB)
#define WS_FLAG_BYTES 65536
#define SLOT_BYTES    32768

#define RELEASE_DRAIN() asm volatile("s_waitcnt vmcnt(0) lgkmcnt(0)" ::: "memory")

__device__ __forceinline__ float sigf(float v) {
  v = fminf(fmaxf(v, -30.f), 30.f);
  return 1.f / (1.f + __expf(-v));
}
__device__ __forceinline__ float tanh_f(float v) {
  v = fminf(fmaxf(v, -15.f), 15.f);
  float e = __expf(2.f * v);
  return (e - 1.f) / (e + 1.f);
}

// wait until all 128 u32 flags (viewed as 64 u64) are >= tgt
__device__ __forceinline__ void wait_ge(const unsigned long long* f, unsigned int tgt, int lane) {
  for (;;) {
    unsigned long long v = __hip_atomic_load(f + lane, __ATOMIC_RELAXED, __HIP_MEMORY_SCOPE_AGENT);
    bool ok = ((unsigned int)v >= tgt) && ((unsigned int)(v >> 32) >= tgt);
    if (__ballot(ok) == ~0ULL) break;
    __builtin_amdgcn_s_sleep(1);
  }
  asm volatile("" ::: "memory");   // compiler acquire: keep h loads after the poll
}

extern "C" __global__ void __launch_bounds__(NTHREADS, 1)
lstm_persist(const float* __restrict__ x,  const float* __restrict__ W0,
             const float* __restrict__ b0, const float* __restrict__ W1,
             const float* __restrict__ b1, const float* __restrict__ Wfc,
             const float* __restrict__ bfc, float* __restrict__ out,
             unsigned char* __restrict__ ws, int Wn, int wmask, int fimask, int slack)
{
  extern __shared__ char lds[];
  f16*   w0l     = (f16*)(lds + LDS_W0_OFF);
  f16*   w1l     = (f16*)(lds + LDS_W1_OFF);
  float* stgbase = (float*)(lds + LDS_STG_OFF);

  const int tid   = threadIdx.x;
  const int wg    = blockIdx.x & (WGS - 1);
  const int cl    = blockIdx.x / WGS;
  const int wave  = tid >> 6;
  const int lane  = tid & 63;
  const int hbase = wg * 8;

  // ---- one-time: gather + transpose this WG's weight columns into LDS (fp16) ----
  {
    const int nl = tid & 31;
    const int wtile = nl >> 4, wi = nl & 15, g = wi >> 2, jj = wi & 3;
    const int col = g * HID + hbase + wtile * 4 + jj;
    for (int k = tid >> 5; k < K0; k += 8)
      w0l[nl * KP0 + k] = (f16)W0[(size_t)k * GATES + col];
    for (int k = tid >> 5; k < K1; k += 8)
      w1l[nl * KP1 + k] = (f16)W1[(size_t)k * GATES + col];
  }
  __syncthreads();   // last block-wide sync; waves run independently below

  // ---- per-wave constants ----
  const int layer = wave >> 1;
  const int tile  = wave & 1;
  const int cb    = hbase + tile * 4;
  const int wid   = wg * 2 + tile;            // producer-wave flag index (0..127)
  const int erow  = lane >> 2;
  const int ehc   = lane & 3;
  const int hcol  = cb + ehc;
  const float* bsrc = layer ? b1 : b0;
  const float bg0 = bsrc[0 * HID + hcol];
  const float bg1 = bsrc[1 * HID + hcol];
  const float bg2 = bsrc[2 * HID + hcol];
  const float bg3 = bsrc[3 * HID + hcol];
  float cstate = 0.f;
  float* stg = stgbase + wave * (16 * 17);

  const int fm  = lane & 15;
  const int q8  = (lane >> 4) * 8;
  const int brow = cl * BPC + fm;

  unsigned char* hby = ws + WS_FLAG_BYTES;
  unsigned int*  f0s = (unsigned int*)(ws + (size_t)cl * 8192);
  unsigned int*  f1s = (unsigned int*)(ws + (size_t)cl * 8192 + 4096);
  const unsigned long long* f0c = (const unsigned long long*)f0s;
  const unsigned long long* f1c = (const unsigned long long*)f1s;

  auto slotp = [&](int lyr, int t, int hl) -> f16* {
    return (f16*)(hby + ((size_t)((cl * 2 + lyr) * Wn + (t & wmask)) << 15) + (hl << 14));
  };

  // epilogue: acc -> gates -> (h, cstate) -> versioned slot store
  auto do_epilogue = [&](f32x4 acc, int t) {
    #pragma unroll
    for (int r = 0; r < 4; ++r)
      stg[((lane >> 4) * 4 + r) * 17 + fm] = acc[r];
    float iv = stg[erow * 17 + 0 + ehc]  + bg0;
    float fv = stg[erow * 17 + 4 + ehc]  + bg1;
    float gv = stg[erow * 17 + 8 + ehc]  + bg2;
    float ov = stg[erow * 17 + 12 + ehc] + bg3;
    float ig = sigf(iv), fg = sigf(fv), gg = tanh_f(gv), og = sigf(ov);
    cstate = fg * cstate + ig * gg;
    float h = og * tanh_f(cstate);

    const int src0 = fm * 4 + ((lane >> 4) & 1) * 2;
    float ha = __shfl(h, src0, 64);
    float hb = __shfl(h, src0 + 1, 64);
    if (lane < 32) {
      const int wrow = lane & 15, wpair = lane >> 4;
      f16* phi = slotp(layer, t, 0);
      f16* plo = slotp(layer, t, 1);
      f16 hah = (f16)ha; f16 hal = (f16)(ha - (float)hah);
      f16 hbh = (f16)hb; f16 hbl = (f16)(hb - (float)hbh);
      unsigned int hw = (unsigned int)__builtin_bit_cast(unsigned short, hah) |
                        ((unsigned int)__builtin_bit_cast(unsigned short, hbh) << 16);
      unsigned int lw = (unsigned int)__builtin_bit_cast(unsigned short, hal) |
                        ((unsigned int)__builtin_bit_cast(unsigned short, hbl) << 16);
      const int coff = wrow * HID + cb + wpair * 2;
      __hip_atomic_store((unsigned int*)(phi + coff), hw, __ATOMIC_RELAXED, __HIP_MEMORY_SCOPE_AGENT);
      __hip_atomic_store((unsigned int*)(plo + coff), lw, __ATOMIC_RELAXED, __HIP_MEMORY_SCOPE_AGENT);
    }
    RELEASE_DRAIN();   // h stores ack'd at coherence point before flag store
  };

  if (layer == 0) {
    for (int t = 0; t < S_LEN; ++t) {
      if (t && (t & fimask) == 0)
        __builtin_amdgcn_fence(__ATOMIC_ACQUIRE, "agent");  // slot-reuse invalidate (every W/2)
      f32x4 acc = {0.f, 0.f, 0.f, 0.f};
      // x part first: independent of the recurrence
      const float* xr = x + ((size_t)brow * S_LEN + t) * IN_D + q8;
      #pragma unroll
      for (int kb = 0; kb < 2; ++kb) {
        f32x4 xa = *(const f32x4*)(xr + kb * 32);
        f32x4 xb = *(const f32x4*)(xr + kb * 32 + 4);
        f16x8 a = { (f16)xa[0], (f16)xa[1], (f16)xa[2], (f16)xa[3],
                    (f16)xb[0], (f16)xb[1], (f16)xb[2], (f16)xb[3] };
        f16x8 bf = *(const f16x8*)(w0l + (tile * 16 + fm) * KP0 + kb * 32 + q8);
        acc = __builtin_amdgcn_mfma_f32_16x16x32_f16(a, bf, acc, 0, 0, 0);
      }
      if (t) {
        wait_ge(f0c, (unsigned)t, lane);                    // h0(t-1) ready
        if (t > slack) wait_ge(f1c, (unsigned)(t - slack), lane);  // window back-pressure
        const f16* hpi = slotp(0, t - 1, 0);
        const f16* hpl = slotp(0, t - 1, 1);
        #pragma unroll 4
        for (int kb = 0; kb < 16; ++kb) {
          const int k = kb * 32 + q8;
          f16x8 bf = *(const f16x8*)(w0l + (tile * 16 + fm) * KP0 + IN_D + k);
          f16x8 ah = *(const f16x8*)(hpi + fm * HID + k);
          f16x8 al = *(const f16x8*)(hpl + fm * HID + k);
          acc = __builtin_amdgcn_mfma_f32_16x16x32_f16(ah, bf, acc, 0, 0, 0);
          acc = __builtin_amdgcn_mfma_f32_16x16x32_f16(al, bf, acc, 0, 0, 0);
        }
      }
      do_epilogue(acc, t);
      if (lane == 0)
        __hip_atomic_store(f0s + wid, (unsigned)(t + 1), __ATOMIC_RELAXED, __HIP_MEMORY_SCOPE_AGENT);
    }
  } else {
    for (int t = 0; t < S_LEN; ++t) {
      if (t && (t & fimask) == 0)
        __builtin_amdgcn_fence(__ATOMIC_ACQUIRE, "agent");
      f32x4 acc = {0.f, 0.f, 0.f, 0.f};
      wait_ge(f0c, (unsigned)(t + 1), lane);                // h0(t) ready
      {
        const f16* h0i = slotp(0, t, 0);
        const f16* h0l = slotp(0, t, 1);
        #pragma unroll 4
        for (int kb = 0; kb < 16; ++kb) {
          const int k = kb * 32 + q8;
          f16x8 bf = *(const f16x8*)(w1l + (tile * 16 + fm) * KP1 + k);
          f16x8 ah = *(const f16x8*)(h0i + fm * HID + k);
          f16x8 al = *(const f16x8*)(h0l + fm * HID + k);
          acc = __builtin_amdgcn_mfma_f32_16x16x32_f16(ah, bf, acc, 0, 0, 0);
          acc = __builtin_amdgcn_mfma_f32_16x16x32_f16(al, bf, acc, 0, 0, 0);
        }
      }
      if (t) {
        wait_ge(f1c, (unsigned)t, lane);                    // h1(t-1) ready (peers)
        const f16* h1i = slotp(1, t - 1, 0);
        const f16* h1l = slotp(1, t - 1, 1);
        #pragma unroll 4
        for (int kb = 0; kb < 16; ++kb) {
          const int k = kb * 32 + q8;
          f16x8 bf = *(const f16x8*)(w1l + (tile * 16 + fm) * KP1 + HID + k);
          f16x8 ah = *(const f16x8*)(h1i + fm * HID + k);
          f16x8 al = *(const f16x8*)(h1l + fm * HID + k);
          acc = __builtin_amdgcn_mfma_f32_16x16x32_f16(ah, bf, acc, 0, 0, 0);
          acc = __builtin_amdgcn_mfma_f32_16x16x32_f16(al, bf, acc, 0, 0, 0);
        }
      }
      do_epilogue(acc, t);
      if (lane == 0)
        __hip_atomic_store(f1s + wid, (unsigned)(t + 1), __ATOMIC_RELAXED, __HIP_MEMORY_SCOPE_AGENT);
    }
  }

  // ---- output head: WG0 of each cluster reads h1(511) ----
  if (wg == 0) {
    wait_ge(f1c, (unsigned)S_LEN, lane);
    __builtin_amdgcn_fence(__ATOMIC_ACQUIRE, "agent");
    const f16* h1i = slotp(1, S_LEN - 1, 0);
    const f16* h1l = slotp(1, S_LEN - 1, 1);
    #pragma unroll
    for (int rr = 0; rr < 4; ++rr) {
      const int r = wave * 4 + rr;
      float sum = 0.f;
      for (int k = lane; k < HID; k += 64) {
        float hv = (float)h1i[r * HID + k] + (float)h1l[r * HID + k];
        sum += hv * Wfc[k];
      }
      #pragma unroll
      for (int off = 32; off > 0; off >>= 1)
        sum += __shfl_down(sum, off, 64);
      if (lane == 0) out[cl * BPC + r] = sum + bfc[0];
    }
  }
}

extern "C" void kernel_launch(void* const* d_in, const int* in_sizes, int n_in,
                              void* d_out, int out_size, void* d_ws, size_t ws_size,
                              hipStream_t stream) {
  const float* x   = (const float*)d_in[0];
  const float* W0  = (const float*)d_in[1];
  const float* b0  = (const float*)d_in[2];
  const float* W1  = (const float*)d_in[3];
  const float* b1  = (const float*)d_in[4];
  const float* Wfc = (const float*)d_in[5];
  const float* bfc = (const float*)d_in[6];
  float* out = (float*)d_out;
  unsigned char* ws = (unsigned char*)d_ws;

  (void)in_sizes; (void)n_in; (void)out_size;

  // window size from available workspace (cap 64 slots = 16.8 MB)
  int Wn = 2;
  while (Wn < 64 &&
         WS_FLAG_BYTES + (size_t)(Wn * 2) * (CLUSTERS * 2 * SLOT_BYTES) <= ws_size)
    Wn *= 2;
  int wmask  = Wn - 1;
  int fimask = (Wn >= 4) ? (Wn / 2 - 1) : 0;  // acquire-fence every Wn/2 steps
  int slack  = Wn - 2;

  hipFuncSetAttribute((const void*)lstm_persist,
                      hipFuncAttributeMaxDynamicSharedMemorySize, LDS_TOTAL);

  // zero only the flag region each call (h slots are written before read)
  hipMemsetAsync(ws, 0, WS_FLAG_BYTES, stream);

  void* args[] = { &x, &W0, &b0, &W1, &b1, &Wfc, &bfc, &out, &ws,
                   &Wn, &wmask, &fimask, &slack };
  hipLaunchCooperativeKernel((void*)lstm_persist, dim3(NBLOCKS), dim3(NTHREADS),
                             args, LDS_TOTAL, stream);
}